// Round 12
// baseline (274.284 us; speedup 1.0000x reference)
//
#include <hip/hip_runtime.h>
#include <hip/hip_bf16.h>

// Problem constants (fixed by reference)
#define BB 32
#define DD 64
#define HWHW 4096
#define NPOS 131072
#define NELEM (NPOS * DD)          // 8388608
#define KK 512
#define LOSS_SCALE (1.2f / 8388608.f)
#define DELTA 2.0f                  // >= 2*eps(bf16 dot) with ~3x margin
#define QCAP 4096
#define PT 4                        // position-tiles per wave (64 positions)
#define NTHR 1024                   // 16 waves: 2 code-halves x 8 waves
#define POSB 512                    // positions per block
#define NBLK (NPOS / POSB)          // 256 blocks = 1 per CU (LDS-capped)

typedef __attribute__((ext_vector_type(8))) short short8v;   // 8 bf16
typedef __attribute__((ext_vector_type(4))) float float4v;   // MFMA acc

__device__ inline unsigned short f2bf(float f) {             // fp32->bf16 RNE
    unsigned u = __float_as_uint(f);
    unsigned r = u + 0x7FFFu + ((u >> 16) & 1u);
    return (unsigned short)(r >> 16);
}
__device__ inline float bf2f(unsigned short s) {
    return __uint_as_float(((unsigned)s) << 16);
}
__device__ inline unsigned f2o(float f) {                    // order-preserving f32->u32
    unsigned u = __float_as_uint(f);
    return ((int)u < 0) ? ~u : (u | 0x80000000u);
}

// ---------------------------------------------------------------------------
// Prep: E fp32 -> bf16 (RNE) into ws; ne2h[k] = -0.5*|e_k|^2 (negated -> MFMA
// C-operand and drain addend).
// ---------------------------------------------------------------------------
__global__ __launch_bounds__(256) void vq_prep(const float* __restrict__ emb,
                                               unsigned short* __restrict__ ebf,
                                               float* __restrict__ ne2h) {
    const int t = blockIdx.x * 256 + threadIdx.x;   // 0..8191
    const int row = t >> 4, c = t & 15;
    const float4 v = *(const float4*)(emb + row * DD + c * 4);
    unsigned u0 = (unsigned)f2bf(v.x) | ((unsigned)f2bf(v.y) << 16);
    unsigned u1 = (unsigned)f2bf(v.z) | ((unsigned)f2bf(v.w) << 16);
    *(uint2*)(ebf + row * DD + c * 4) = make_uint2(u0, u1);
    float p = v.x * v.x + v.y * v.y + v.z * v.z + v.w * v.w;
    p += __shfl_xor(p, 1, 64); p += __shfl_xor(p, 2, 64);
    p += __shfl_xor(p, 4, 64); p += __shfl_xor(p, 8, 64);
    if (c == 0) ne2h[row] = -0.5f * p;
}

// ---------------------------------------------------------------------------
// Main. R8's validated two-pass numerics with CODE-SPLIT waves:
//   16 waves = 2 code-halves x 8 waves. Wave (half h, wg) scans codes
//   [256h, 256h+256) for its 64 positions (PT=4). Each wave reads HALF the
//   codebook per pass -> block LDS traffic + per-iter addressing halve vs R8
//   (R8 accounting: LDS ~25K cyc/CU was the largest reducible term).
//   Work (MFMA, extraction) is conserved: 16 iters x 8 MFMA vs 32 x 4.
// Between passes the per-position per-half maxima merge via pmax2[2][512]
// (plain stores, one barrier) -> SAME final-max threshold as R8 -> same
// candidate set (~750/block; R9 lesson: running-max thresholds blow up the
// count -> overflow fallback; final-max is count-stable).
// Scores S^T = E_bf16 * X_bf16^T via mfma_f32_16x16x32_bf16, C = -e2/2.
// LDS swizzle: chunk c of row r at slot (c ^ (r&7)) -> conflict-free b128
// (row index kbase+ct*16+l15 keeps row&7 = l15&7 for both halves).
//   A-frag: row = kbase + ct*16 + (l&15), chunks lg / lg|4.  B-frag: elem j
//   <-> d = h*32+(l>>4)*8+j (same k-map as A -> internal permutation
//   cancels). C/D: col=l&15=position, row=(l>>4)*4+r=code (m89).
// Drain: fp32 rescore of candidates, packed-key LDS atomicMax (monotone f32
// | (511-k) => first-min-index ties). Validated R3-R9 (absmax 1.2e-4).
// ---------------------------------------------------------------------------
__global__ __launch_bounds__(NTHR) void vq_main(
        const float* __restrict__ feat,
        const float* __restrict__ emb,
        const unsigned short* __restrict__ ebf,
        const float* __restrict__ ne2h,
        float* __restrict__ out,
        float* __restrict__ loss) {

    __shared__ uint4 ebf_lds[4096];          // 64 KiB swizzled bf16 codebook
    __shared__ float ne2_lds[KK];            // 2 KiB
    __shared__ float pmax2[2][POSB];         // 4 KiB per-half position maxima
    __shared__ unsigned long long sbest[POSB];
    __shared__ unsigned qbuf[QCAP];
    __shared__ unsigned qcnt;
    __shared__ float wsum[NTHR / 64];

    const int tid = threadIdx.x;
    const int wid = tid >> 6, lane = tid & 63;
    const int l15 = lane & 15, lg = lane >> 4;
    const int half = wid >> 3;               // code-half this wave scans
    const int wg   = wid & 7;                // wave index within half

    // ---- stage codebook into LDS (swizzled) + init ----
    {
        const uint4* src = (const uint4*)ebf;    // 4096 16B chunks
#pragma unroll
        for (int i = 0; i < 4; ++i) {
            const int idx = tid * 4 + i;         // chunk index
            const int row = idx >> 3, c = idx & 7;
            ebf_lds[row * 8 + (c ^ (row & 7))] = src[idx];
        }
    }
    if (tid < KK) ne2_lds[tid] = ne2h[tid];
    if (tid < POSB) sbest[tid] = 0ull;
    if (tid == 0) qcnt = 0u;

    const int pbase = blockIdx.x * POSB;
    const int b     = pbase >> 12;
    const int hwb   = pbase & 4095;
    const float* featB = feat + (size_t)b * DD * HWHW;
    float*       outB  = out  + (size_t)b * DD * HWHW;
    const int wbase = wg * (PT * 16);        // 64 positions per wave
    const int kbase = half * 256;            // first code of this wave's half

    // ---- staging X: 64 positions' B-frags, in 2-tile batches ----
    short8v bx[PT][2];
#pragma unroll
    for (int pp = 0; pp < 2; ++pp) {
        float xv[2][2][8];
#pragma unroll
        for (int q = 0; q < 2; ++q) {
            const int hw = hwb + wbase + (pp * 2 + q) * 16 + l15;
#pragma unroll
            for (int h = 0; h < 2; ++h)
#pragma unroll
                for (int j = 0; j < 8; ++j)
                    xv[q][h][j] = featB[(size_t)(h * 32 + lg * 8 + j) * HWHW + hw];
        }
#pragma unroll
        for (int q = 0; q < 2; ++q)
#pragma unroll
            for (int h = 0; h < 2; ++h) {
                short8v s;
#pragma unroll
                for (int j = 0; j < 8; ++j) s[j] = (short)f2bf(xv[q][h][j]);
                bx[pp * 2 + q][h] = s;
            }
    }

    __syncthreads();   // codebook + init visible

    // per-lane swizzled LDS base slots (row swz = l15&7: kbase+ct*16 ≡ 0 mod 8)
    const int swz = l15 & 7;
    const uint4* a0p = &ebf_lds[(kbase + l15) * 8 + (lg ^ swz)];
    const uint4* a1p = &ebf_lds[(kbase + l15) * 8 + ((lg | 4) ^ swz)];

    // ---- pass 1: branch-free per-position max over this wave's code-half ----
    float M[PT];
#pragma unroll
    for (int pt = 0; pt < PT; ++pt) M[pt] = -3.0e38f;

    short8v a0n = *(const short8v*)a0p;
    short8v a1n = *(const short8v*)a1p;
    float4v ne2n = *(const float4v*)&ne2_lds[kbase + lg * 4];

    for (int ct = 0; ct < 16; ++ct) {
        const short8v a0c = a0n, a1c = a1n;
        const float4v ne2c = ne2n;
        if (ct < 15) {
            a0n = *(const short8v*)(a0p + (ct + 1) * 128);
            a1n = *(const short8v*)(a1p + (ct + 1) * 128);
            ne2n = *(const float4v*)&ne2_lds[kbase + (ct + 1) * 16 + lg * 4];
        }
        float4v acc[PT];
#pragma unroll
        for (int pt = 0; pt < PT; ++pt)
            acc[pt] = __builtin_amdgcn_mfma_f32_16x16x32_bf16(a0c, bx[pt][0], ne2c, 0, 0, 0);
#pragma unroll
        for (int pt = 0; pt < PT; ++pt)
            acc[pt] = __builtin_amdgcn_mfma_f32_16x16x32_bf16(a1c, bx[pt][1], acc[pt], 0, 0, 0);
#pragma unroll
        for (int pt = 0; pt < PT; ++pt) {
            const float m01 = fmaxf(acc[pt][0], acc[pt][1]);
            const float m23 = fmaxf(acc[pt][2], acc[pt][3]);
            M[pt] = fmaxf(M[pt], fmaxf(m01, m23));
        }
    }

    // ---- merge 4 lanes per position, publish per-half max, global merge ----
#pragma unroll
    for (int pt = 0; pt < PT; ++pt) {
        float m = M[pt];
        m = fmaxf(m, __shfl_xor(m, 16, 64));
        m = fmaxf(m, __shfl_xor(m, 32, 64));
        if (lg == 0) pmax2[half][wbase + pt * 16 + l15] = m;
    }
    __syncthreads();

    float thr[PT];
#pragma unroll
    for (int pt = 0; pt < PT; ++pt) {
        const int pos = wbase + pt * 16 + l15;
        thr[pt] = fmaxf(pmax2[0][pos], pmax2[1][pos]) - DELTA;
    }

    // ---- pass 2: bitwise-identical recompute, enqueue candidates ----
    a0n = *(const short8v*)a0p;
    a1n = *(const short8v*)a1p;
    ne2n = *(const float4v*)&ne2_lds[kbase + lg * 4];

    for (int ct = 0; ct < 16; ++ct) {
        const short8v a0c = a0n, a1c = a1n;
        const float4v ne2c = ne2n;
        if (ct < 15) {
            a0n = *(const short8v*)(a0p + (ct + 1) * 128);
            a1n = *(const short8v*)(a1p + (ct + 1) * 128);
            ne2n = *(const float4v*)&ne2_lds[kbase + (ct + 1) * 16 + lg * 4];
        }
        float4v acc[PT];
#pragma unroll
        for (int pt = 0; pt < PT; ++pt)
            acc[pt] = __builtin_amdgcn_mfma_f32_16x16x32_bf16(a0c, bx[pt][0], ne2c, 0, 0, 0);
#pragma unroll
        for (int pt = 0; pt < PT; ++pt)
            acc[pt] = __builtin_amdgcn_mfma_f32_16x16x32_bf16(a1c, bx[pt][1], acc[pt], 0, 0, 0);
#pragma unroll
        for (int pt = 0; pt < PT; ++pt) {
            const float m01 = fmaxf(acc[pt][0], acc[pt][1]);
            const float m23 = fmaxf(acc[pt][2], acc[pt][3]);
            const float mx  = fmaxf(m01, m23);
            if (__any(mx >= thr[pt])) {
#pragma unroll
                for (int r = 0; r < 4; ++r) {
                    if (acc[pt][r] >= thr[pt]) {
                        const unsigned idx  = atomicAdd(&qcnt, 1u);
                        const unsigned code = (unsigned)(kbase + ct * 16 + lg * 4 + r);
                        const unsigned pos  = (unsigned)(wbase + pt * 16 + l15);
                        if (idx < QCAP) qbuf[idx] = (pos << 9) | code;
                    }
                }
            }
        }
    }

    __syncthreads();

    // ---- drain: fp32 rescore of candidates, resolve winner per position ----
    // Fallback (prob ~0): queue overflow -> rescore all (pos, code) pairs.
    const unsigned qn  = qcnt;
    const bool     ovf = (qn > (unsigned)QCAP);
    const unsigned n   = ovf ? (unsigned)(POSB * KK) : qn;
    for (unsigned i = tid; i < n; i += NTHR) {
        unsigned p, k;
        if (ovf) { p = i >> 9; k = i & 511u; }
        else     { const unsigned e = qbuf[i]; p = e >> 9; k = e & 511u; }
        const float4* er4 = (const float4*)(emb + k * DD);
        const float*  fp  = featB + hwb + p;
        float a0 = 0.f, a1 = 0.f;
#pragma unroll 4
        for (int dq = 0; dq < 16; ++dq) {
            const float4 e4 = er4[dq];
            a0 = fmaf(fp[(size_t)(4 * dq    ) * HWHW], e4.x, a0);
            a1 = fmaf(fp[(size_t)(4 * dq + 1) * HWHW], e4.y, a1);
            a0 = fmaf(fp[(size_t)(4 * dq + 2) * HWHW], e4.z, a0);
            a1 = fmaf(fp[(size_t)(4 * dq + 3) * HWHW], e4.w, a1);
        }
        const float sc = (a0 + a1) + ne2_lds[k];
        const unsigned long long key =
            ((unsigned long long)f2o(sc) << 32) | (unsigned long long)(511u - k);
        atomicMax(&sbest[p], key);   // ties -> larger (511-k) -> smaller k
    }

    __syncthreads();

    // ---- epilogue: st = e[k*] (exact), loss from in-register bf16 x.
    //      Each position written once: wave handles 2 of its 4 pos-tiles,
    //      selected by its code-half (partner wave covers the other 2). ----
    float lsum = 0.f;
#pragma unroll
    for (int q = 0; q < 2; ++q) {
        const int pt = half * 2 + q;
        const int pl = wbase + pt * 16 + l15;
        const int hw = hwb + pl;
        const unsigned long long key = sbest[pl];
        const unsigned k = 511u - (unsigned)key;
        const float* er = emb + k * DD;
#pragma unroll
        for (int h = 0; h < 2; ++h) {
            const short8v xs = bx[pt][h];
#pragma unroll
            for (int jj = 0; jj < 2; ++jj) {
                const float4v ev = *(const float4v*)(er + h * 32 + lg * 8 + jj * 4);
#pragma unroll
                for (int c = 0; c < 4; ++c) {
                    const int j = jj * 4 + c;
                    const int d = h * 32 + lg * 8 + j;
                    const float q2 = ev[c];
                    outB[(size_t)d * HWHW + hw] = q2;
                    const float diff = q2 - bf2f((unsigned short)xs[j]);
                    lsum = fmaf(diff, diff, lsum);
                }
            }
        }
    }

#pragma unroll
    for (int off = 32; off > 0; off >>= 1) lsum += __shfl_down(lsum, off, 64);
    if (lane == 0) wsum[wid] = lsum;
    __syncthreads();
    if (tid == 0) {
        float s = 0.f;
#pragma unroll
        for (int w = 0; w < NTHR / 64; ++w) s += wsum[w];
        atomicAdd(loss, s * LOSS_SCALE);
    }
}

// ---------------------------------------------------------------------------
extern "C" void kernel_launch(void* const* d_in, const int* in_sizes, int n_in,
                              void* d_out, int out_size, void* d_ws, size_t ws_size,
                              hipStream_t stream) {
    const float* feat = (const float*)d_in[0];   // (32,64,64,64) fp32
    const float* emb  = (const float*)d_in[1];   // (512,64) fp32
    float* out  = (float*)d_out;                 // [0..NELEM) = st, [NELEM] = loss
    float* loss = out + NELEM;

    unsigned short* ebf  = (unsigned short*)d_ws;                // 64 KiB bf16 codebook
    float*          ne2h = (float*)((char*)d_ws + 64 * 1024);    // 2 KiB, -|e|^2/2

    hipMemsetAsync(loss, 0, sizeof(float), stream);
    vq_prep<<<dim3(32), dim3(256), 0, stream>>>(emb, ebf, ne2h);
    vq_main<<<dim3(NBLK), dim3(NTHR), 0, stream>>>(feat, emb, ebf, ne2h, out, loss);
}

// Round 13
// 148.775 us; speedup vs baseline: 1.8436x; 1.8436x over previous
//
#include <hip/hip_runtime.h>
#include <hip/hip_bf16.h>
#include <hip/hip_fp16.h>

// Problem constants (fixed by reference)
#define BB 32
#define DD 64
#define HWHW 4096
#define NPOS 131072
#define NELEM (NPOS * DD)          // 8388608
#define KK 512
#define LOSS_SCALE (1.2f / 8388608.f)
#define DELTA 2.0f                  // >= 2*eps(bf16 dot) with ~3x margin
#define MARG 0.0625f                // fp16 cache rounding margin (2x worst ulp)
#define QCAP 4096
#define PT 2                        // position-tiles per wave (R12 lesson: PT=4 spills at 1024thr)
#define NTHR 1024                   // 16 waves
#define POSB 512                    // positions per block
#define NBLK (NPOS / POSB)          // 256 blocks = 1 per CU

typedef __attribute__((ext_vector_type(8))) short short8v;   // 8 bf16
typedef __attribute__((ext_vector_type(4))) float float4v;   // MFMA acc

__device__ inline unsigned short f2bf(float f) {             // fp32->bf16 RNE
    unsigned u = __float_as_uint(f);
    unsigned r = u + 0x7FFFu + ((u >> 16) & 1u);
    return (unsigned short)(r >> 16);
}
__device__ inline float bf2f(unsigned short s) {
    return __uint_as_float(((unsigned)s) << 16);
}
__device__ inline unsigned f2o(float f) {                    // order-preserving f32->u32
    unsigned u = __float_as_uint(f);
    return ((int)u < 0) ? ~u : (u | 0x80000000u);
}
__device__ inline unsigned packh2(float a, float b) {        // 2x fp16 RNE packed
    unsigned lo = (unsigned)__half_as_ushort(__float2half(a));
    unsigned hi = (unsigned)__half_as_ushort(__float2half(b));
    return lo | (hi << 16);
}

// ---------------------------------------------------------------------------
// Prep: E fp32 -> bf16 (RNE) into ws; ne2h[k] = -0.5*|e_k|^2 (negated -> MFMA
// C-operand and drain addend).
// ---------------------------------------------------------------------------
__global__ __launch_bounds__(256) void vq_prep(const float* __restrict__ emb,
                                               unsigned short* __restrict__ ebf,
                                               float* __restrict__ ne2h) {
    const int t = blockIdx.x * 256 + threadIdx.x;   // 0..8191
    const int row = t >> 4, c = t & 15;
    const float4 v = *(const float4*)(emb + row * DD + c * 4);
    unsigned u0 = (unsigned)f2bf(v.x) | ((unsigned)f2bf(v.y) << 16);
    unsigned u1 = (unsigned)f2bf(v.z) | ((unsigned)f2bf(v.w) << 16);
    *(uint2*)(ebf + row * DD + c * 4) = make_uint2(u0, u1);
    float p = v.x * v.x + v.y * v.y + v.z * v.z + v.w * v.w;
    p += __shfl_xor(p, 1, 64); p += __shfl_xor(p, 2, 64);
    p += __shfl_xor(p, 4, 64); p += __shfl_xor(p, 8, 64);
    if (c == 0) ne2h[row] = -0.5f * p;
}

// ---------------------------------------------------------------------------
// Main = R8 (best measured, 65us; clean traffic) + tile-max cache skip.
// Pass 1 (full unroll): per (lane, pt, ct) the max of the lane's 4 codes
// (m4) is packed fp16 into cache_u[32] (32 VGPR; 64+32=96 < 128 cap ->
// no spill, unlike R12's PT=4). Pass 2 tests cache >= thr - MARG and skips
// tiles with no possible candidate: fp16 RNE err <= 0.031 for |s|<=96,
// MARG=0.0625 -> skip is conservative; candidate set IDENTICAL to R8's.
// P(pt-tile executes) ~ 0.52 -> pass-2 MFMA/extract ~halves.
// Scores S^T = E_bf16 * X_bf16^T via mfma_f32_16x16x32_bf16, C = -e2/2.
// LDS swizzle: chunk c of row r at slot (c ^ (r&7)) -> conflict-free b128.
//   A-frag (E): row=ct*16+(l&15), chunks lg / lg|4.  B-frag (X): elem j <->
//   d = h*32+(l>>4)*8+j (same k-map -> permutation cancels).
//   C/D: col=l&15=position, row=(l>>4)*4+r=code (m89).
// Drain: fp32 rescore of candidates, packed-key LDS atomicMax (monotone f32
// | (511-k) => first-min-index ties). Numerics validated R3-R12 (absmax
// 1.2e-4, index-exact).
// ---------------------------------------------------------------------------
__global__ __launch_bounds__(NTHR) void vq_main(
        const float* __restrict__ feat,
        const float* __restrict__ emb,
        const unsigned short* __restrict__ ebf,
        const float* __restrict__ ne2h,
        float* __restrict__ out,
        float* __restrict__ loss) {

    __shared__ uint4 ebf_lds[4096];          // 64 KiB swizzled bf16 codebook
    __shared__ float ne2_lds[KK];            // 2 KiB
    __shared__ unsigned long long sbest[POSB];
    __shared__ unsigned qbuf[QCAP];
    __shared__ unsigned qcnt;
    __shared__ float wsum[NTHR / 64];

    const int tid = threadIdx.x;
    const int wid = tid >> 6, lane = tid & 63;
    const int l15 = lane & 15, lg = lane >> 4;

    // ---- stage codebook into LDS (swizzled) + init ----
    {
        const uint4* src = (const uint4*)ebf;    // 4096 16B chunks
#pragma unroll
        for (int i = 0; i < 4; ++i) {
            const int idx = tid * 4 + i;         // chunk index
            const int row = idx >> 3, c = idx & 7;
            ebf_lds[row * 8 + (c ^ (row & 7))] = src[idx];
        }
    }
    if (tid < KK) ne2_lds[tid] = ne2h[tid];
    if (tid < POSB) sbest[tid] = 0ull;
    if (tid == 0) qcnt = 0u;

    const int pbase = blockIdx.x * POSB;
    const int b     = pbase >> 12;
    const int hwb   = pbase & 4095;
    const float* featB = feat + (size_t)b * DD * HWHW;
    float*       outB  = out  + (size_t)b * DD * HWHW;
    const int wbase = wid * (PT * 16);   // 32 positions per wave

    // ---- staging X: hoist all 32 feat loads, convert to bf16 B-frags ----
    float xv[PT][2][8];
#pragma unroll
    for (int pt = 0; pt < PT; ++pt) {
        const int hw = hwb + wbase + pt * 16 + l15;
#pragma unroll
        for (int h = 0; h < 2; ++h)
#pragma unroll
            for (int j = 0; j < 8; ++j)
                xv[pt][h][j] = featB[(size_t)(h * 32 + lg * 8 + j) * HWHW + hw];
    }
    short8v bx[PT][2];
#pragma unroll
    for (int pt = 0; pt < PT; ++pt)
#pragma unroll
        for (int h = 0; h < 2; ++h) {
            short8v s;
#pragma unroll
            for (int j = 0; j < 8; ++j) s[j] = (short)f2bf(xv[pt][h][j]);
            bx[pt][h] = s;
        }

    __syncthreads();   // codebook + init visible

    // per-lane swizzled LDS base slots (constant across ct: ct*16 ≡ 0 mod 8)
    const int swz = l15 & 7;
    const uint4* a0p = &ebf_lds[l15 * 8 + (lg ^ swz)];
    const uint4* a1p = &ebf_lds[l15 * 8 + ((lg | 4) ^ swz)];

    // ---- pass 1: branch-free per-position max + fp16 tile-max cache ----
    float M0 = -3.0e38f, M1 = -3.0e38f;
    unsigned cache_u[32];                    // compile-time indexed (full unroll)

#pragma unroll
    for (int ct = 0; ct < 32; ++ct) {
        const short8v a0c = *(const short8v*)(a0p + ct * 128);
        const short8v a1c = *(const short8v*)(a1p + ct * 128);
        const float4v ne2c = *(const float4v*)&ne2_lds[ct * 16 + lg * 4];
        float4v acc0 = __builtin_amdgcn_mfma_f32_16x16x32_bf16(a0c, bx[0][0], ne2c, 0, 0, 0);
        acc0 = __builtin_amdgcn_mfma_f32_16x16x32_bf16(a1c, bx[0][1], acc0, 0, 0, 0);
        float4v acc1 = __builtin_amdgcn_mfma_f32_16x16x32_bf16(a0c, bx[1][0], ne2c, 0, 0, 0);
        acc1 = __builtin_amdgcn_mfma_f32_16x16x32_bf16(a1c, bx[1][1], acc1, 0, 0, 0);
        const float m4a = fmaxf(fmaxf(acc0[0], acc0[1]), fmaxf(acc0[2], acc0[3]));
        const float m4b = fmaxf(fmaxf(acc1[0], acc1[1]), fmaxf(acc1[2], acc1[3]));
        M0 = fmaxf(M0, m4a);
        M1 = fmaxf(M1, m4b);
        cache_u[ct] = packh2(m4a, m4b);
    }

    // ---- merge across the 4 lanes holding the same position column ----
    float thr[PT];
    {
        float m = M0;
        m = fmaxf(m, __shfl_xor(m, 16, 64));
        m = fmaxf(m, __shfl_xor(m, 32, 64));
        thr[0] = m - DELTA;
        m = M1;
        m = fmaxf(m, __shfl_xor(m, 16, 64));
        m = fmaxf(m, __shfl_xor(m, 32, 64));
        thr[1] = m - DELTA;
    }
    const float tt0 = thr[0] - MARG, tt1 = thr[1] - MARG;

    // ---- pass 2: cache-gated recompute, enqueue candidates ----
#pragma unroll
    for (int ct = 0; ct < 32; ++ct) {
        const unsigned cw = cache_u[ct];
        const float c0 = __half2float(__ushort_as_half((unsigned short)(cw & 0xffffu)));
        const float c1 = __half2float(__ushort_as_half((unsigned short)(cw >> 16)));
        const bool t0 = __any(c0 >= tt0);
        const bool t1 = __any(c1 >= tt1);
        if (t0 | t1) {
            const short8v a0c = *(const short8v*)(a0p + ct * 128);
            const short8v a1c = *(const short8v*)(a1p + ct * 128);
            const float4v ne2c = *(const float4v*)&ne2_lds[ct * 16 + lg * 4];
            if (t0) {
                float4v acc = __builtin_amdgcn_mfma_f32_16x16x32_bf16(a0c, bx[0][0], ne2c, 0, 0, 0);
                acc = __builtin_amdgcn_mfma_f32_16x16x32_bf16(a1c, bx[0][1], acc, 0, 0, 0);
                const float mx = fmaxf(fmaxf(acc[0], acc[1]), fmaxf(acc[2], acc[3]));
                if (mx >= thr[0]) {
#pragma unroll
                    for (int r = 0; r < 4; ++r) {
                        if (acc[r] >= thr[0]) {
                            const unsigned idx  = atomicAdd(&qcnt, 1u);
                            const unsigned code = (unsigned)(ct * 16 + lg * 4 + r);
                            const unsigned pos  = (unsigned)(wbase + l15);
                            if (idx < QCAP) qbuf[idx] = (pos << 9) | code;
                        }
                    }
                }
            }
            if (t1) {
                float4v acc = __builtin_amdgcn_mfma_f32_16x16x32_bf16(a0c, bx[1][0], ne2c, 0, 0, 0);
                acc = __builtin_amdgcn_mfma_f32_16x16x32_bf16(a1c, bx[1][1], acc, 0, 0, 0);
                const float mx = fmaxf(fmaxf(acc[0], acc[1]), fmaxf(acc[2], acc[3]));
                if (mx >= thr[1]) {
#pragma unroll
                    for (int r = 0; r < 4; ++r) {
                        if (acc[r] >= thr[1]) {
                            const unsigned idx  = atomicAdd(&qcnt, 1u);
                            const unsigned code = (unsigned)(ct * 16 + lg * 4 + r);
                            const unsigned pos  = (unsigned)(wbase + 16 + l15);
                            if (idx < QCAP) qbuf[idx] = (pos << 9) | code;
                        }
                    }
                }
            }
        }
    }

    __syncthreads();

    // ---- drain: fp32 rescore of candidates, resolve winner per position ----
    // Fallback (prob ~0): queue overflow -> rescore all (pos, code) pairs.
    const unsigned qn  = qcnt;
    const bool     ovf = (qn > (unsigned)QCAP);
    const unsigned n   = ovf ? (unsigned)(POSB * KK) : qn;
    for (unsigned i = tid; i < n; i += NTHR) {
        unsigned p, k;
        if (ovf) { p = i >> 9; k = i & 511u; }
        else     { const unsigned e = qbuf[i]; p = e >> 9; k = e & 511u; }
        const float4* er4 = (const float4*)(emb + k * DD);
        const float*  fp  = featB + hwb + p;
        float a0 = 0.f, a1 = 0.f;
#pragma unroll 4
        for (int dq = 0; dq < 16; ++dq) {
            const float4 e4 = er4[dq];
            a0 = fmaf(fp[(size_t)(4 * dq    ) * HWHW], e4.x, a0);
            a1 = fmaf(fp[(size_t)(4 * dq + 1) * HWHW], e4.y, a1);
            a0 = fmaf(fp[(size_t)(4 * dq + 2) * HWHW], e4.z, a0);
            a1 = fmaf(fp[(size_t)(4 * dq + 3) * HWHW], e4.w, a1);
        }
        const float sc = (a0 + a1) + ne2_lds[k];
        const unsigned long long key =
            ((unsigned long long)f2o(sc) << 32) | (unsigned long long)(511u - k);
        atomicMax(&sbest[p], key);   // ties -> larger (511-k) -> smaller k
    }

    __syncthreads();

    // ---- epilogue: st = e[k*] (exact), loss from in-register bf16 x ----
    float lsum = 0.f;
#pragma unroll
    for (int pt = 0; pt < PT; ++pt) {
        const int pl = wbase + pt * 16 + l15;
        const int hw = hwb + pl;
        const unsigned long long key = sbest[pl];
        const unsigned k = 511u - (unsigned)key;
        const float* er = emb + k * DD;
#pragma unroll
        for (int h = 0; h < 2; ++h) {
            const short8v xs = bx[pt][h];
#pragma unroll
            for (int jj = 0; jj < 2; ++jj) {
                const float4v ev = *(const float4v*)(er + h * 32 + lg * 8 + jj * 4);
#pragma unroll
                for (int c = 0; c < 4; ++c) {
                    const int j = jj * 4 + c;
                    const int d = h * 32 + lg * 8 + j;
                    const float q = ev[c];
                    outB[(size_t)d * HWHW + hw] = q;
                    const float diff = q - bf2f((unsigned short)xs[j]);
                    lsum = fmaf(diff, diff, lsum);
                }
            }
        }
    }

#pragma unroll
    for (int off = 32; off > 0; off >>= 1) lsum += __shfl_down(lsum, off, 64);
    if (lane == 0) wsum[wid] = lsum;
    __syncthreads();
    if (tid == 0) {
        float s = 0.f;
#pragma unroll
        for (int w = 0; w < NTHR / 64; ++w) s += wsum[w];
        atomicAdd(loss, s * LOSS_SCALE);
    }
}

// ---------------------------------------------------------------------------
extern "C" void kernel_launch(void* const* d_in, const int* in_sizes, int n_in,
                              void* d_out, int out_size, void* d_ws, size_t ws_size,
                              hipStream_t stream) {
    const float* feat = (const float*)d_in[0];   // (32,64,64,64) fp32
    const float* emb  = (const float*)d_in[1];   // (512,64) fp32
    float* out  = (float*)d_out;                 // [0..NELEM) = st, [NELEM] = loss
    float* loss = out + NELEM;

    unsigned short* ebf  = (unsigned short*)d_ws;                // 64 KiB bf16 codebook
    float*          ne2h = (float*)((char*)d_ws + 64 * 1024);    // 2 KiB, -|e|^2/2

    hipMemsetAsync(loss, 0, sizeof(float), stream);
    vq_prep<<<dim3(32), dim3(256), 0, stream>>>(emb, ebf, ne2h);
    vq_main<<<dim3(NBLK), dim3(NTHR), 0, stream>>>(feat, emb, ebf, ne2h, out, loss);
}